// Round 7
// baseline (184.083 us; speedup 1.0000x reference)
//
#include <hip/hip_runtime.h>
#include <math.h>

#define NEG_SLOPE 0.2f

typedef _Float16 half8 __attribute__((ext_vector_type(8)));
typedef _Float16 half2v __attribute__((ext_vector_type(2)));
typedef float floatx4 __attribute__((ext_vector_type(4)));

__device__ __forceinline__ float dot4f(float4 a, float4 b) {
    return a.x * b.x + a.y * b.y + a.z * b.z + a.w * b.w;
}
static __device__ __forceinline__ unsigned short f2h(float x) {
    _Float16 h = (_Float16)x;               // RNE
    return __builtin_bit_cast(unsigned short, h);
}
static __device__ __forceinline__ float h2f(unsigned short u) {
    _Float16 h = __builtin_bit_cast(_Float16, u);
    return (float)h;
}

// ---------------------------------------------------------------------------
// Kernel 0: build the 17-panel fp16 B matrix in MFMA-B-fragment order.
//  blocks 0..255  : panels 0..15 = W^T packed: Wtp[cp][kc][cm][j]=W[kc*8+j][cp*16+cm]
//  blocks 256..271: panel 16, col t: t<8 -> wl[:,t]=W[:,t*32:+32]@al[t],
//                   t>=8 -> wr[:,t-8] likewise. So GEMM cols 256..271 ARE el|er.
// ---------------------------------------------------------------------------
__global__ void k_prep(const float* __restrict__ W,
                       const float* __restrict__ al,
                       const float* __restrict__ ar,
                       unsigned short* __restrict__ Wtp) {
    const int k = threadIdx.x;      // 256
    if (blockIdx.x < 256) {
        const int c = blockIdx.x;
        Wtp[(size_t)(c >> 4) * 4096 + (k >> 3) * 128 + (c & 15) * 8 + (k & 7)] =
            f2h(W[(size_t)k * 256 + c]);
    } else {
        const int t = blockIdx.x - 256;          // 0..15
        const float* att = (t < 8) ? al : ar;
        const int h = (t < 8) ? t : t - 8;
        float s = 0.f;
        for (int o = 0; o < 32; ++o) s += W[(size_t)k * 256 + h * 32 + o] * att[h * 32 + o];
        Wtp[(size_t)16 * 4096 + (k >> 3) * 128 + t * 8 + (k & 7)] = f2h(s);
    }
}

// ---------------------------------------------------------------------------
// Kernel 1: exact fp32 y (selection-critical) + gate; writes gated fp16 row
// directly in MFMA-A-fragment PANEL order so k_gemm needs no LDS staging:
//   Ahp half-offset for (node n: P=n>>4, m=n&15; element k):
//     P*4096 + (k>>3)*128 + m*8 + (k&7)
// One wave per node; lane l holds k = 4l..4l+3 -> 8B store at
//   P*4096 + (l>>1)*128 + m*8 + (l&1)*4   (8B aligned, block fills full lines)
// ---------------------------------------------------------------------------
__global__ __launch_bounds__(256) void k_score(const float4* __restrict__ feat4,
                                               const float4* __restrict__ p4,
                                               float* __restrict__ y,
                                               unsigned short* __restrict__ Ahp,
                                               int N) {
    const int lane = threadIdx.x & 63;
    const int n = blockIdx.x * 4 + (threadIdx.x >> 6);
    if (n >= N) return;
    float4 f = feat4[(size_t)n * 64 + lane];
    float4 p = p4[lane];
    float dp = dot4f(f, p);
    float pp = dot4f(p, p);
#pragma unroll
    for (int off = 32; off; off >>= 1) {
        dp += __shfl_xor(dp, off, 64);
        pp += __shfl_xor(pp, off, 64);
    }
    float yv = fabsf(dp) / sqrtf(pp);
    if (lane == 0) y[n] = yv;
    float g = 2.0f / (1.0f + __expf(-yv));
    ushort4 u;
    u.x = f2h(g * f.x);
    u.y = f2h(g * f.y);
    u.z = f2h(g * f.z);
    u.w = f2h(g * f.w);
    const int P = n >> 4, m = n & 15;
    size_t off = (size_t)P * 4096 + (lane >> 1) * 128 + m * 8 + (lane & 1) * 4;
    *(ushort4*)(Ahp + off) = u;
}

// ---------------------------------------------------------------------------
// Kernel 2: pure-MFMA GEMM, no LDS, one barrier. Block = 4 waves = 32 rows
// (2 A-panels). Wave w: B-panels 4w..4w+3; wave 3 additionally panel 16
// (el|er columns). All frag loads are coalesced 16B global loads (Ahp/Wtp
// panel order). fth is written IN PLACE over Ahp (row 16P..16P+15 occupy the
// same 8KB as panel P); the single __syncthreads (which drains vmcnt first)
// guarantees every wave's A-loads completed before any wave stores.
// NOTE: Ahp/fth deliberately NOT __restrict__ (they alias).
// ---------------------------------------------------------------------------
__global__ __launch_bounds__(256) void k_gemm(const unsigned short* Ahp,
                                              const unsigned short* __restrict__ Wtp,
                                              unsigned short* fth,
                                              unsigned short* __restrict__ elh,
                                              unsigned short* __restrict__ erh,
                                              int N) {
    const int lane = threadIdx.x & 63;
    const int w = threadIdx.x >> 6;
    const int l16 = lane & 15, quad = lane >> 4;
    const int n0 = blockIdx.x * 32;
    const int P0 = n0 >> 4;
    const int P1 = (n0 + 16 < N) ? P0 + 1 : P0;   // tail clamp (results masked)

    floatx4 acc[2][4];
    floatx4 acce[2];
#pragma unroll
    for (int mt = 0; mt < 2; ++mt) {
        acce[mt] = (floatx4){0.f, 0.f, 0.f, 0.f};
#pragma unroll
        for (int ct = 0; ct < 4; ++ct) acc[mt][ct] = (floatx4){0.f, 0.f, 0.f, 0.f};
    }

    const unsigned short* abase0 = Ahp + (size_t)P0 * 4096 + quad * 128 + l16 * 8;
    const unsigned short* abase1 = Ahp + (size_t)P1 * 4096 + quad * 128 + l16 * 8;
    const unsigned short* bbase  = Wtp + (size_t)(w * 4) * 4096 + quad * 128 + l16 * 8;
    const unsigned short* ebase  = Wtp + (size_t)16 * 4096 + quad * 128 + l16 * 8;

#pragma unroll
    for (int ks = 0; ks < 256; ks += 32) {
        const int ko = (ks >> 3) * 128;
        half8 a0 = *(const half8*)(abase0 + ko);
        half8 a1 = *(const half8*)(abase1 + ko);
        half8 b0 = *(const half8*)(bbase + ko);
        half8 b1 = *(const half8*)(bbase + ko + 4096);
        half8 b2 = *(const half8*)(bbase + ko + 8192);
        half8 b3 = *(const half8*)(bbase + ko + 12288);
        acc[0][0] = __builtin_amdgcn_mfma_f32_16x16x32_f16(a0, b0, acc[0][0], 0, 0, 0);
        acc[0][1] = __builtin_amdgcn_mfma_f32_16x16x32_f16(a0, b1, acc[0][1], 0, 0, 0);
        acc[0][2] = __builtin_amdgcn_mfma_f32_16x16x32_f16(a0, b2, acc[0][2], 0, 0, 0);
        acc[0][3] = __builtin_amdgcn_mfma_f32_16x16x32_f16(a0, b3, acc[0][3], 0, 0, 0);
        acc[1][0] = __builtin_amdgcn_mfma_f32_16x16x32_f16(a1, b0, acc[1][0], 0, 0, 0);
        acc[1][1] = __builtin_amdgcn_mfma_f32_16x16x32_f16(a1, b1, acc[1][1], 0, 0, 0);
        acc[1][2] = __builtin_amdgcn_mfma_f32_16x16x32_f16(a1, b2, acc[1][2], 0, 0, 0);
        acc[1][3] = __builtin_amdgcn_mfma_f32_16x16x32_f16(a1, b3, acc[1][3], 0, 0, 0);
        if (w == 3) {
            half8 be = *(const half8*)(ebase + ko);
            acce[0] = __builtin_amdgcn_mfma_f32_16x16x32_f16(a0, be, acce[0], 0, 0, 0);
            acce[1] = __builtin_amdgcn_mfma_f32_16x16x32_f16(a1, be, acce[1], 0, 0, 0);
        }
    }

    __syncthreads();   // vmcnt-drained barrier: all A-loads done before stores

    // fth row-major [row][256] fp16 (over the Ahp bytes of the same panels)
#pragma unroll
    for (int mt = 0; mt < 2; ++mt)
#pragma unroll
        for (int ct = 0; ct < 4; ++ct)
#pragma unroll
            for (int i = 0; i < 4; ++i) {
                int row = n0 + mt * 16 + quad * 4 + i;
                if (row < N)
                    fth[(size_t)row * 256 + (w * 4 + ct) * 16 + l16] = f2h(acc[mt][ct][i]);
            }
    if (w == 3) {
#pragma unroll
        for (int mt = 0; mt < 2; ++mt)
#pragma unroll
            for (int i = 0; i < 4; ++i) {
                int row = n0 + mt * 16 + quad * 4 + i;
                if (row < N) {
                    unsigned short v = f2h(acce[mt][i]);
                    if (l16 < 8) elh[(size_t)row * 8 + l16] = v;
                    else         erh[(size_t)row * 8 + (l16 - 8)] = v;
                }
            }
    }
}

// ---------------------------------------------------------------------------
// Kernel 3: per node — top-8 neighbors by y[src] via ballot radix-select
// (exact 8th-largest; ties only arise from duplicate neighbor ids, which are
// aggregation-invariant), gather fp16 ft rows + fp16 el, leaky-relu, softmax
// over k, packed-fp16 weighted sum, elu, nontemporal store.
// ---------------------------------------------------------------------------
__global__ __launch_bounds__(256) void k_aggr(const int* __restrict__ nbr,
                                              const float* __restrict__ y,
                                              const uint2* __restrict__ fth2,
                                              const unsigned short* __restrict__ elh,
                                              const unsigned short* __restrict__ erh,
                                              floatx4* __restrict__ out4,
                                              int N) {
    const int lane = threadIdx.x & 63;
    const int n = blockIdx.x * 4 + (threadIdx.x >> 6);
    if (n >= N) return;
    const int h = lane >> 3;

    const int s = nbr[(size_t)n * 64 + lane];
    const unsigned int key = __float_as_uint(y[s]);   // y >= 0 -> order-monotone

    unsigned int t = 0u;
#pragma unroll
    for (int b = 30; b >= 0; --b) {
        unsigned int cand = t | (1u << b);
        unsigned long long m = __ballot(key >= cand);
        if (__popcll(m) >= 8) t = cand;
    }
    const unsigned long long gtmask = __ballot(key > t);
    const int ngt = __popcll(gtmask);                       // <= 7
    const unsigned long long eqmask = __ballot(key == t);
    const unsigned long long below = (1ull << lane) - 1ull;
    const int eqrank = __popcll(eqmask & below);
    const bool in8 = (key > t) | ((key == t) & (eqrank < 8 - ngt));
    unsigned long long selmask = __ballot(in8);             // exactly 8 bits

    int srck[8];
#pragma unroll
    for (int k = 0; k < 8; ++k) {
        int l = __ffsll((long long)selmask) - 1;
        srck[k] = __shfl(s, l, 64);
        selmask &= selmask - 1ull;
    }

    uint2 vk[8];
#pragma unroll
    for (int k = 0; k < 8; ++k) vk[k] = fth2[(size_t)srck[k] * 64 + lane];

    const float erv = h2f(erh[(size_t)n * 8 + h]);
    float e[8];
#pragma unroll
    for (int k = 0; k < 8; ++k) {
        float ev = h2f(elh[(size_t)srck[k] * 8 + h]) + erv;
        e[k] = ev > 0.f ? ev : NEG_SLOPE * ev;
    }

    float m = e[0];
#pragma unroll
    for (int k = 1; k < 8; ++k) m = fmaxf(m, e[k]);
    float sum = 0.f;
#pragma unroll
    for (int k = 0; k < 8; ++k) {
        e[k] = __expf(e[k] - m);
        sum += e[k];
    }
    const float inv = 1.0f / sum;

    half2v acc0 = (half2v){(_Float16)0, (_Float16)0};
    half2v acc1 = acc0;
#pragma unroll
    for (int k = 0; k < 8; ++k) {
        _Float16 ah = (_Float16)(e[k] * inv);
        half2v a2 = {ah, ah};
        acc0 += a2 * __builtin_bit_cast(half2v, vk[k].x);
        acc1 += a2 * __builtin_bit_cast(half2v, vk[k].y);
    }
    floatx4 r;
    r[0] = (float)acc0[0];
    r[1] = (float)acc0[1];
    r[2] = (float)acc1[0];
    r[3] = (float)acc1[1];
    r[0] = r[0] > 0.f ? r[0] : __expf(r[0]) - 1.f;
    r[1] = r[1] > 0.f ? r[1] : __expf(r[1]) - 1.f;
    r[2] = r[2] > 0.f ? r[2] : __expf(r[2]) - 1.f;
    r[3] = r[3] > 0.f ? r[3] : __expf(r[3]) - 1.f;
    __builtin_nontemporal_store(r, &out4[(size_t)n * 64 + lane]);
}

// ---------------------------------------------------------------------------
extern "C" void kernel_launch(void* const* d_in, const int* in_sizes, int n_in,
                              void* d_out, int out_size, void* d_ws, size_t ws_size,
                              hipStream_t stream) {
    const float* feat = (const float*)d_in[0];   // [N,256] fp32
    const int* nbr    = (const int*)d_in[1];     // [N,64] int32
    const float* p    = (const float*)d_in[2];   // [1,256]
    const float* W    = (const float*)d_in[3];   // [256,256]
    const float* al   = (const float*)d_in[4];   // [1,8,32]
    const float* ar   = (const float*)d_in[5];   // [1,8,32]

    const int N = in_sizes[0] / 256;

    // ws: y[N] f32 | Wtp[17*4096 fp16] | elh[8N fp16] | erh[8N fp16]
    //     | Ahp/fth union [256N fp16]            total ~27.5 MB
    float* y = (float*)d_ws;
    unsigned short* Wtp = (unsigned short*)(y + N);
    unsigned short* elh = Wtp + 17 * 4096;
    unsigned short* erh = elh + (size_t)N * 8;
    unsigned short* Ahp = erh + (size_t)N * 8;   // fth aliases this region

    k_prep<<<272, 256, 0, stream>>>(W, al, ar, Wtp);
    k_score<<<(N + 3) / 4, 256, 0, stream>>>((const float4*)feat, (const float4*)p,
                                             y, Ahp, N);
    k_gemm<<<(N + 31) / 32, 256, 0, stream>>>(Ahp, Wtp, Ahp /*fth in place*/,
                                              elh, erh, N);
    k_aggr<<<(N + 3) / 4, 256, 0, stream>>>(nbr, y, (const uint2*)Ahp, elh, erh,
                                            (floatx4*)d_out, N);
}